// Round 17
// baseline (539.478 us; speedup 1.0000x reference)
//
#include <hip/hip_runtime.h>

typedef unsigned short u16;
typedef unsigned int u32;
typedef __bf16 bf16x8 __attribute__((ext_vector_type(8)));
typedef float f32x4 __attribute__((ext_vector_type(4)));

#define N 4096
#define KD 128
#define NSTRIP 32
#define G 2              // cols per lane
#define W 128            // strip width (u16); 256B per row
#define ROWB 256
#define CH 32            // rows per block
#define NCHUNK 128       // N/CH
#define NBLK 130         // ceil((N+63)/CH)
#define RINGROWS 128     // 4 slots x 32
#define WINB 32768       // RINGROWS*ROWB
#define HUGEV 3.0e38f
#define TS 128
#define PADK 136

__device__ __forceinline__ u16 f2bf(float v) {
  u32 u = __float_as_uint(v);
  u += 0x7fffu + ((u >> 16) & 1u);   // RNE
  return (u16)(u >> 16);
}
__device__ __forceinline__ float bf2f(u16 b) { return __uint_as_float(((u32)b) << 16); }
__device__ __forceinline__ float bfround(float v) { return bf2f(f2bf(v)); }

__device__ __forceinline__ float dpp_shr1(float oldv, float src) {
  return __int_as_float(__builtin_amdgcn_update_dpp(
      __float_as_int(oldv), __float_as_int(src), 0x138, 0xF, 0xF, false));
}

__device__ __forceinline__ void gload_lds16(const void* g, void* l) {
  __builtin_amdgcn_global_load_lds((const __attribute__((address_space(1))) u32*)g,
                                   (__attribute__((address_space(3))) u32*)l, 16, 0, 0);
}

// ---------------- norms (of bf16-rounded points) + edge sentinel init ----------------
__global__ __launch_bounds__(256) void norms_kernel(const float* __restrict__ pred,
                                                    const float* __restrict__ tgt,
                                                    float* __restrict__ na, float* __restrict__ nb,
                                                    float* __restrict__ edgeG) {
  const int t = blockIdx.x * 256 + threadIdx.x;
  if (t < NSTRIP * N) edgeG[t] = -1.0f;          // sentinel: DP values always >= 0
  int gw = blockIdx.x * 4 + (threadIdx.x >> 6);
  int lane = threadIdx.x & 63;
  const float* base = (gw < N) ? (pred + (size_t)gw * KD) : (tgt + (size_t)(gw - N) * KD);
  float2 v = ((const float2*)base)[lane];
  float x = bfround(v.x), y = bfround(v.y);
  float s = x * x + y * y;
  #pragma unroll
  for (int off = 32; off > 0; off >>= 1) s += __shfl_xor(s, off);
  if (lane == 0) { if (gw < N) na[gw] = s; else nb[gw - N] = s; }
}

// ---------------- C2 = |a|^2 + |b|^2 - 2 a.b  (bf16, row-major) ----------------
__global__ __launch_bounds__(256) void gemm_kernel(const float* __restrict__ A, const float* __restrict__ B,
                                                   const float* __restrict__ na, const float* __restrict__ nb,
                                                   u16* __restrict__ C2) {
  __shared__ u16 As[TS * PADK];
  __shared__ u16 Bs[TS * PADK];
  const int bi = blockIdx.y, bj = blockIdx.x;
  const int tid = threadIdx.x;
  {
    int row = tid >> 1, half = (tid & 1) * 64;
    const float* ga = A + (size_t)(bi * TS + row) * KD + half;
    const float* gb = B + (size_t)(bj * TS + row) * KD + half;
    u16* la = As + row * PADK + half;
    u16* lb = Bs + row * PADK + half;
    #pragma unroll
    for (int v = 0; v < 16; ++v) {
      float4 fa = ((const float4*)ga)[v];
      float4 fb = ((const float4*)gb)[v];
      *(ushort4*)(la + v * 4) = make_ushort4(f2bf(fa.x), f2bf(fa.y), f2bf(fa.z), f2bf(fa.w));
      *(ushort4*)(lb + v * 4) = make_ushort4(f2bf(fb.x), f2bf(fb.y), f2bf(fb.z), f2bf(fb.w));
    }
  }
  __syncthreads();
  const int wid = tid >> 6, lane = tid & 63;
  const int wr = (wid >> 1) * 64, wc = (wid & 1) * 64;
  const int l15 = lane & 15, l4 = lane >> 4;
  f32x4 acc[4][4] = {};
  #pragma unroll
  for (int ks = 0; ks < 4; ++ks) {
    bf16x8 af[4], bq[4];
    const int ko = ks * 32 + l4 * 8;
    #pragma unroll
    for (int m = 0; m < 4; ++m) af[m] = *(const bf16x8*)(As + (wr + m * 16 + l15) * PADK + ko);
    #pragma unroll
    for (int n = 0; n < 4; ++n) bq[n] = *(const bf16x8*)(Bs + (wc + n * 16 + l15) * PADK + ko);
    #pragma unroll
    for (int m = 0; m < 4; ++m)
      #pragma unroll
      for (int n = 0; n < 4; ++n)
        acc[m][n] = __builtin_amdgcn_mfma_f32_16x16x32_bf16(af[m], bq[n], acc[m][n], 0, 0, 0);
  }
  #pragma unroll
  for (int m = 0; m < 4; ++m) {
    const int r0 = bi * TS + wr + m * 16 + l4 * 4;
    #pragma unroll
    for (int n = 0; n < 4; ++n) {
      const int col = bj * TS + wc + n * 16 + l15;
      const float nbv = nb[col];
      #pragma unroll
      for (int e = 0; e < 4; ++e) {
        const int r = r0 + e;
        float d2v = fmaxf(na[r] + nbv - 2.0f * acc[m][n][e], 0.0f);
        C2[(size_t)r * N + col] = f2bf(d2v);
      }
    }
  }
}

// ---------------- wavefront DP over squared distances ----------------
// 32 WGs x 1 wave; strip = 128 cols (2 per lane); CH=32 rows per block.
// Lattice-distributed recurrence (carried cycle = 4 ops):
//   m0 = min3(D0, Lp, Lc); n0 = max(c0, m0); x = min(D1, D0)
//   n1 = max(c1, min(x, n0)) = max3(c1, min(x,c0), min(x,m0))
#define STEP2(CU, EV) { \
  const float c0 = __uint_as_float((CU) << 16); \
  const float c1 = __uint_as_float((CU) & 0xFFFF0000u); \
  const float Lc = dpp_shr1((EV), D1); \
  const float x  = fminf(D1, D0); \
  const float m0 = fminf(fminf(D0, Lp), Lc); \
  const float n0 = fmaxf(c0, m0); \
  const float n1 = fmaxf(fmaxf(c1, fminf(x, c0)), fminf(x, m0)); \
  D0 = n0; D1 = n1; Lp = Lc; \
}

#define LDGRP2(EA, EB, CV, GG) { \
  EA = *(const float4*)(elds + 8 * (GG)); \
  EB = *(const float4*)(elds + 8 * (GG) + 4); \
  CV##0 = *(const u32*)(clb + cbs); \
  CV##1 = *(const u32*)(clb + cbs + 256); \
  CV##2 = *(const u32*)(clb + cbs + 512); \
  CV##3 = *(const u32*)(clb + cbs + 768); \
  CV##4 = *(const u32*)(clb + cbs + 1024); \
  CV##5 = *(const u32*)(clb + cbs + 1280); \
  CV##6 = *(const u32*)(clb + cbs + 1536); \
  CV##7 = *(const u32*)(clb + cbs + 1792); \
  cbs = (cbs + 2048) & 0x7FFFu; \
}

#define CGRP2(EA, EB, CV) { \
  float t0, t1, t2, t3, t4, t5, t6, t7; \
  STEP2(CV##0, EA.x); t0 = D1; \
  STEP2(CV##1, EA.y); t1 = D1; \
  STEP2(CV##2, EA.z); t2 = D1; \
  STEP2(CV##3, EA.w); t3 = D1; \
  STEP2(CV##4, EB.x); t4 = D1; \
  STEP2(CV##5, EB.y); t5 = D1; \
  STEP2(CV##6, EB.z); t6 = D1; \
  STEP2(CV##7, EB.w); t7 = D1; \
  if (e63) { \
    eout[eg + 0] = t0; eout[eg + 1] = t1; eout[eg + 2] = t2; eout[eg + 3] = t3; \
    eout[eg + 4] = t4; eout[eg + 5] = t5; eout[eg + 6] = t6; eout[eg + 7] = t7; \
  } \
  eg += 8; \
}

__global__ __launch_bounds__(64) void dp_kernel(const u16* __restrict__ C2, float* __restrict__ edgeG,
                                                float* __restrict__ out) {
  __shared__ u16 win[(RINGROWS + 8) * W];             // 34 KB: 4-slot ring + 8 mirror rows
  __shared__ __align__(16) float elds[CH];
  __shared__ __align__(16) float eout[CH];
  const int bid = blockIdx.x;
  const int S = ((bid & 7) << 2) | (bid >> 3);        // 4 consecutive strips per XCD
  const int lane = threadIdx.x;
  const u16* cbase = C2 + (size_t)S * W;
  const char* clb = (const char*)win;
  const bool s0 = (S == 0);
  const bool do_edge = (S != NSTRIP - 1);
  const bool e63 = do_edge && (lane == 63);
  const bool l32 = lane < 32;
  float* eB = edgeG + (size_t)S * N;
  float* eI = edgeG + (size_t)(S - 1) * N;            // producer edges (S>0 only)

  if (s0 && l32) elds[lane] = (lane == 0) ? -HUGEV : HUGEV;   // row-0 seed

  float D0 = HUGEV, D1 = HUGEV, Lp = HUGEV;

  auto STAGE = [&](int c) {
    const int lrow = lane >> 4, lcol = (lane & 15) * 8;
    const u16* g0 = cbase + (size_t)(c * CH + lrow) * N + lcol;
    u16* l0 = win + (c & 3) * (CH * W);
    #pragma unroll
    for (int n = 0; n < 8; ++n) gload_lds16(g0 + (size_t)(4 * n) * N, l0 + n * 512);
    if ((c & 3) == 0) {   // mirror ring rows 0..7 -> rows 128..135
      u16* lm = win + RINGROWS * W;
      #pragma unroll
      for (int n = 0; n < 2; ++n) gload_lds16(g0 + (size_t)(4 * n) * N, lm + n * 512);
    }
  };

  // prologue: prefetch block-0 edges (data-as-flag) + stage chunk 0
  float v0p = HUGEV;
  if (S > 0 && l32)
    v0p = __hip_atomic_fetch_add(eI + lane, 0.0f, __ATOMIC_RELAXED, __HIP_MEMORY_SCOPE_AGENT);
  STAGE(0);

  for (int q = 0; q < NBLK; ++q) {
    const int s_lo = q * CH;
    const int s_hi = (s_lo + CH < 4159) ? (s_lo + CH) : 4159;

    // (A) drain: STAGE(q), prefetch RMW, last publish — all >= 1 block old
    asm volatile("s_waitcnt vmcnt(0)" ::: "memory");
    __builtin_amdgcn_sched_barrier(0);

    // (B) validate prefetched edges (sentinel = not yet produced); commit to LDS
    if (S > 0 && q <= 127) {
      int it = 0;
      while (__any(v0p < 0.0f)) {
        __builtin_amdgcn_s_sleep(1);
        if (l32)
          v0p = __hip_atomic_fetch_add(eI + q * 32 + lane, 0.0f,
                                       __ATOMIC_RELAXED, __HIP_MEMORY_SCOPE_AGENT);
        if (++it > (1 << 20)) break;
      }
      if (l32) elds[lane] = v0p;
    }
    if (s0 && q == 1 && lane == 0) elds[0] = HUGEV;   // retire row-0 seed

    // (C) issue next edge prefetch + next chunk stage (race-free: slot (q+1)&3 unread)
    if (S > 0 && q + 1 <= 127 && l32)
      v0p = __hip_atomic_fetch_add(eI + (q + 1) * 32 + lane, 0.0f,
                                   __ATOMIC_RELAXED, __HIP_MEMORY_SCOPE_AGENT);
    else
      v0p = HUGEV;
    if (q + 1 < NCHUNK) STAGE(q + 1);

    asm volatile("s_waitcnt lgkmcnt(0)" ::: "memory");
    __builtin_amdgcn_sched_barrier(0);

    // (D) compute
    u32 cbs = (((u32)(s_lo - lane)) & 127) * ROWB + lane * (G * 2);
    int eg = 0;

    if (q >= 2 && q <= 127) {
      // fast path: all lanes active; 2-deep LDS pipeline with named buffers
      float4 eaA, ebA, eaB, ebB;
      u32 cA0, cA1, cA2, cA3, cA4, cA5, cA6, cA7;
      u32 cB0, cB1, cB2, cB3, cB4, cB5, cB6, cB7;
      LDGRP2(eaA, ebA, cA, 0)
      LDGRP2(eaB, ebB, cB, 1)
      CGRP2(eaA, ebA, cA)
      LDGRP2(eaA, ebA, cA, 2)
      CGRP2(eaB, ebB, cB)
      LDGRP2(eaB, ebB, cB, 3)
      CGRP2(eaA, ebA, cA)
      CGRP2(eaB, ebB, cB)
    } else {
      // guarded path (q in {0,1,128,129})
      for (int s = s_lo; s < s_hi; ++s) {
        const u32 cu = *(const u32*)(clb + cbs);
        cbs = (cbs + ROWB) & 0x7FFFu;
        const float ev = elds[s & (CH - 1)];
        const float c0 = __uint_as_float(cu << 16);
        const float c1 = __uint_as_float(cu & 0xFFFF0000u);
        const float Lc = dpp_shr1(ev, D1);
        const float x  = fminf(D1, D0);
        const float m0 = fminf(fminf(D0, Lp), Lc);
        const float n0 = fmaxf(c0, m0);
        const float n1 = fmaxf(fmaxf(c1, fminf(x, c0)), fminf(x, m0));
        const int ii = s - lane;
        const bool act = (u32)ii < (u32)N;
        Lp = (s0 && lane == 0) ? HUGEV : Lc;
        if (act) { D0 = n0; D1 = n1; }
        if (e63 && act) eout[s - s_lo] = n1;
      }
    }

    // (E) publish rows [s_lo-63, s_lo-32]: plain stores, data IS the flag
    if (do_edge) {
      asm volatile("s_waitcnt lgkmcnt(0)" ::: "memory");
      __builtin_amdgcn_sched_barrier(0);
      const int r = s_lo - 63 + lane;
      if (l32 && r >= 0 && r < N) {
        const float v = eout[lane];
        __hip_atomic_store(eB + r, v, __ATOMIC_RELAXED, __HIP_MEMORY_SCOPE_AGENT);
      }
    }
  }

  if (S == NSTRIP - 1 && lane == 63) out[0] = sqrtf(fmaxf(D1, 0.0f));
}

extern "C" void kernel_launch(void* const* d_in, const int* in_sizes, int n_in,
                              void* d_out, int out_size, void* d_ws, size_t ws_size,
                              hipStream_t stream) {
  const float* pred = (const float*)d_in[0];
  const float* tgt  = (const float*)d_in[1];
  char* ws = (char*)d_ws;
  u16* C2   = (u16*)ws;                                   // 32 MB row-major d2 (bf16)
  float* na = (float*)(ws + (size_t)N * N * 2);
  float* nb = na + N;
  float* edgeG = nb + N;                                  // 32*N floats, sentinel-init'd
  float* out = (float*)d_out;

  hipLaunchKernelGGL(norms_kernel, dim3(2048), dim3(256), 0, stream, pred, tgt, na, nb, edgeG);
  hipLaunchKernelGGL(gemm_kernel, dim3(32, 32), dim3(256), 0, stream, pred, tgt, na, nb, C2);
  hipLaunchKernelGGL(dp_kernel, dim3(NSTRIP), dim3(64), 0, stream, C2, edgeG, out);
}

// Round 18
// 511.171 us; speedup vs baseline: 1.0554x; 1.0554x over previous
//
#include <hip/hip_runtime.h>

typedef unsigned short u16;
typedef unsigned int u32;
typedef __bf16 bf16x8 __attribute__((ext_vector_type(8)));
typedef float f32x4 __attribute__((ext_vector_type(4)));

#define N 4096
#define KD 128
#define NSTRIP 32
#define G 2              // cols per lane
#define W 128            // strip width (u16); 256B per row
#define ROWB 256
#define CH 32            // rows per block
#define NCHUNK 128       // N/CH
#define NBLK 130         // ceil((N+63)/CH)
#define RINGROWS 128     // 4 slots x 32
#define WINB 32768       // RINGROWS*ROWB
#define HUGEV 3.0e38f
#define TS 128
#define PADK 136

__device__ __forceinline__ u16 f2bf(float v) {
  u32 u = __float_as_uint(v);
  u += 0x7fffu + ((u >> 16) & 1u);   // RNE
  return (u16)(u >> 16);
}
__device__ __forceinline__ float bf2f(u16 b) { return __uint_as_float(((u32)b) << 16); }
__device__ __forceinline__ float bfround(float v) { return bf2f(f2bf(v)); }

__device__ __forceinline__ float dpp_shr1(float oldv, float src) {
  return __int_as_float(__builtin_amdgcn_update_dpp(
      __float_as_int(oldv), __float_as_int(src), 0x138, 0xF, 0xF, false));
}

__device__ __forceinline__ void gload_lds16(const void* g, void* l) {
  __builtin_amdgcn_global_load_lds((const __attribute__((address_space(1))) u32*)g,
                                   (__attribute__((address_space(3))) u32*)l, 16, 0, 0);
}

// ---------------- norms (of bf16-rounded points) + edge sentinel init ----------------
__global__ __launch_bounds__(256) void norms_kernel(const float* __restrict__ pred,
                                                    const float* __restrict__ tgt,
                                                    float* __restrict__ na, float* __restrict__ nb,
                                                    float* __restrict__ edgeG) {
  const int t = blockIdx.x * 256 + threadIdx.x;
  if (t < NSTRIP * N) edgeG[t] = -1.0f;          // sentinel: DP values always >= 0
  int gw = blockIdx.x * 4 + (threadIdx.x >> 6);
  int lane = threadIdx.x & 63;
  const float* base = (gw < N) ? (pred + (size_t)gw * KD) : (tgt + (size_t)(gw - N) * KD);
  float2 v = ((const float2*)base)[lane];
  float x = bfround(v.x), y = bfround(v.y);
  float s = x * x + y * y;
  #pragma unroll
  for (int off = 32; off > 0; off >>= 1) s += __shfl_xor(s, off);
  if (lane == 0) { if (gw < N) na[gw] = s; else nb[gw - N] = s; }
}

// ---------------- C2 = |a|^2 + |b|^2 - 2 a.b  (bf16, row-major) ----------------
__global__ __launch_bounds__(256) void gemm_kernel(const float* __restrict__ A, const float* __restrict__ B,
                                                   const float* __restrict__ na, const float* __restrict__ nb,
                                                   u16* __restrict__ C2) {
  __shared__ u16 As[TS * PADK];
  __shared__ u16 Bs[TS * PADK];
  const int bi = blockIdx.y, bj = blockIdx.x;
  const int tid = threadIdx.x;
  {
    int row = tid >> 1, half = (tid & 1) * 64;
    const float* ga = A + (size_t)(bi * TS + row) * KD + half;
    const float* gb = B + (size_t)(bj * TS + row) * KD + half;
    u16* la = As + row * PADK + half;
    u16* lb = Bs + row * PADK + half;
    #pragma unroll
    for (int v = 0; v < 16; ++v) {
      float4 fa = ((const float4*)ga)[v];
      float4 fb = ((const float4*)gb)[v];
      *(ushort4*)(la + v * 4) = make_ushort4(f2bf(fa.x), f2bf(fa.y), f2bf(fa.z), f2bf(fa.w));
      *(ushort4*)(lb + v * 4) = make_ushort4(f2bf(fb.x), f2bf(fb.y), f2bf(fb.z), f2bf(fb.w));
    }
  }
  __syncthreads();
  const int wid = tid >> 6, lane = tid & 63;
  const int wr = (wid >> 1) * 64, wc = (wid & 1) * 64;
  const int l15 = lane & 15, l4 = lane >> 4;
  f32x4 acc[4][4] = {};
  #pragma unroll
  for (int ks = 0; ks < 4; ++ks) {
    bf16x8 af[4], bq[4];
    const int ko = ks * 32 + l4 * 8;
    #pragma unroll
    for (int m = 0; m < 4; ++m) af[m] = *(const bf16x8*)(As + (wr + m * 16 + l15) * PADK + ko);
    #pragma unroll
    for (int n = 0; n < 4; ++n) bq[n] = *(const bf16x8*)(Bs + (wc + n * 16 + l15) * PADK + ko);
    #pragma unroll
    for (int m = 0; m < 4; ++m)
      #pragma unroll
      for (int n = 0; n < 4; ++n)
        acc[m][n] = __builtin_amdgcn_mfma_f32_16x16x32_bf16(af[m], bq[n], acc[m][n], 0, 0, 0);
  }
  #pragma unroll
  for (int m = 0; m < 4; ++m) {
    const int r0 = bi * TS + wr + m * 16 + l4 * 4;
    #pragma unroll
    for (int n = 0; n < 4; ++n) {
      const int col = bj * TS + wc + n * 16 + l15;
      const float nbv = nb[col];
      #pragma unroll
      for (int e = 0; e < 4; ++e) {
        const int r = r0 + e;
        float d2v = fmaxf(na[r] + nbv - 2.0f * acc[m][n][e], 0.0f);
        C2[(size_t)r * N + col] = f2bf(d2v);
      }
    }
  }
}

// ---------------- wavefront DP over squared distances ----------------
// 32 WGs x 1 wave; strip = 128 cols (2 per lane); CH=32 rows per block.
// Direct recurrence: D[i][j] = max(c, min3(up, upleft, left)) — 2 VALU/cell.
#define STEP2(CU, EV) { \
  const float c0 = __uint_as_float((CU) << 16); \
  const float c1 = __uint_as_float((CU) & 0xFFFF0000u); \
  const float Lc = dpp_shr1((EV), D1); \
  const float n0 = fmaxf(c0, fminf(fminf(D0, Lp), Lc)); \
  const float n1 = fmaxf(c1, fminf(fminf(D1, D0), n0)); \
  D0 = n0; D1 = n1; Lp = Lc; \
}

#define LDGRP2(EA, EB, CV, GG) { \
  EA = *(const float4*)(elds + 8 * (GG)); \
  EB = *(const float4*)(elds + 8 * (GG) + 4); \
  CV##0 = *(const u32*)(clb + cbs); \
  CV##1 = *(const u32*)(clb + cbs + 256); \
  CV##2 = *(const u32*)(clb + cbs + 512); \
  CV##3 = *(const u32*)(clb + cbs + 768); \
  CV##4 = *(const u32*)(clb + cbs + 1024); \
  CV##5 = *(const u32*)(clb + cbs + 1280); \
  CV##6 = *(const u32*)(clb + cbs + 1536); \
  CV##7 = *(const u32*)(clb + cbs + 1792); \
  cbs = (cbs + 2048) & 0x7FFFu; \
}

#define CGRP2(EA, EB, CV) { \
  float t0, t1, t2, t3, t4, t5, t6, t7; \
  STEP2(CV##0, EA.x); t0 = D1; \
  STEP2(CV##1, EA.y); t1 = D1; \
  STEP2(CV##2, EA.z); t2 = D1; \
  STEP2(CV##3, EA.w); t3 = D1; \
  STEP2(CV##4, EB.x); t4 = D1; \
  STEP2(CV##5, EB.y); t5 = D1; \
  STEP2(CV##6, EB.z); t6 = D1; \
  STEP2(CV##7, EB.w); t7 = D1; \
  if (e63) { \
    eout[eg + 0] = t0; eout[eg + 1] = t1; eout[eg + 2] = t2; eout[eg + 3] = t3; \
    eout[eg + 4] = t4; eout[eg + 5] = t5; eout[eg + 6] = t6; eout[eg + 7] = t7; \
  } \
  eg += 8; \
}

__global__ __launch_bounds__(64) void dp_kernel(const u16* __restrict__ C2, float* __restrict__ edgeG,
                                                float* __restrict__ out) {
  __shared__ u16 win[(RINGROWS + 8) * W];             // 34 KB: 4-slot ring + 8 mirror rows
  __shared__ __align__(16) float elds[CH];
  __shared__ __align__(16) float eout[CH];
  const int bid = blockIdx.x;
  const int S = ((bid & 7) << 2) | (bid >> 3);        // 4 consecutive strips per XCD
  const int lane = threadIdx.x;
  const u16* cbase = C2 + (size_t)S * W;
  const char* clb = (const char*)win;
  const bool s0 = (S == 0);
  const bool do_edge = (S != NSTRIP - 1);
  const bool e63 = do_edge && (lane == 63);
  const bool l32 = lane < 32;
  float* eB = edgeG + (size_t)S * N;
  float* eI = edgeG + (size_t)(S - 1) * N;            // producer edges (S>0 only)

  if (s0 && l32) elds[lane] = (lane == 0) ? -HUGEV : HUGEV;   // row-0 seed

  float D0 = HUGEV, D1 = HUGEV, Lp = HUGEV;

  auto STAGE = [&](int c) {
    const int lrow = lane >> 4, lcol = (lane & 15) * 8;
    const u16* g0 = cbase + (size_t)(c * CH + lrow) * N + lcol;
    u16* l0 = win + (c & 3) * (CH * W);
    #pragma unroll
    for (int n = 0; n < 8; ++n) gload_lds16(g0 + (size_t)(4 * n) * N, l0 + n * 512);
    if ((c & 3) == 0) {   // mirror ring rows 0..7 -> rows 128..135
      u16* lm = win + RINGROWS * W;
      #pragma unroll
      for (int n = 0; n < 2; ++n) gload_lds16(g0 + (size_t)(4 * n) * N, lm + n * 512);
    }
  };

  // prologue: prefetch block-0 edges (data-as-flag) + stage chunk 0
  float v0p = HUGEV;
  if (S > 0 && l32)
    v0p = __hip_atomic_fetch_add(eI + lane, 0.0f, __ATOMIC_RELAXED, __HIP_MEMORY_SCOPE_AGENT);
  STAGE(0);

  for (int q = 0; q < NBLK; ++q) {
    const int s_lo = q * CH;
    const int s_hi = (s_lo + CH < 4159) ? (s_lo + CH) : 4159;

    // (A) drain: STAGE(q), prefetch RMW, last publish — all >= 1 block old
    asm volatile("s_waitcnt vmcnt(0)" ::: "memory");
    __builtin_amdgcn_sched_barrier(0);

    // (B) validate prefetched edges (sentinel = not yet produced); commit to LDS
    if (S > 0 && q <= 127) {
      int it = 0;
      while (__any(v0p < 0.0f)) {
        __builtin_amdgcn_s_sleep(1);
        if (l32)
          v0p = __hip_atomic_fetch_add(eI + q * 32 + lane, 0.0f,
                                       __ATOMIC_RELAXED, __HIP_MEMORY_SCOPE_AGENT);
        if (++it > (1 << 20)) break;
      }
      if (l32) elds[lane] = v0p;
    }
    if (s0 && q == 1 && lane == 0) elds[0] = HUGEV;   // retire row-0 seed

    // (C) issue next edge prefetch + next chunk stage (race-free: slot (q+1)&3 unread)
    if (S > 0 && q + 1 <= 127 && l32)
      v0p = __hip_atomic_fetch_add(eI + (q + 1) * 32 + lane, 0.0f,
                                   __ATOMIC_RELAXED, __HIP_MEMORY_SCOPE_AGENT);
    else
      v0p = HUGEV;
    if (q + 1 < NCHUNK) STAGE(q + 1);

    asm volatile("s_waitcnt lgkmcnt(0)" ::: "memory");
    __builtin_amdgcn_sched_barrier(0);

    // (D) compute
    u32 cbs = (((u32)(s_lo - lane)) & 127) * ROWB + lane * (G * 2);
    int eg = 0;

    if (q >= 2 && q <= 127) {
      // fast path: all lanes active; 2-deep LDS pipeline with named buffers
      float4 eaA, ebA, eaB, ebB;
      u32 cA0, cA1, cA2, cA3, cA4, cA5, cA6, cA7;
      u32 cB0, cB1, cB2, cB3, cB4, cB5, cB6, cB7;
      LDGRP2(eaA, ebA, cA, 0)
      LDGRP2(eaB, ebB, cB, 1)
      CGRP2(eaA, ebA, cA)
      LDGRP2(eaA, ebA, cA, 2)
      CGRP2(eaB, ebB, cB)
      LDGRP2(eaB, ebB, cB, 3)
      CGRP2(eaA, ebA, cA)
      CGRP2(eaB, ebB, cB)
    } else {
      // guarded path (q in {0,1,128,129})
      for (int s = s_lo; s < s_hi; ++s) {
        const u32 cu = *(const u32*)(clb + cbs);
        cbs = (cbs + ROWB) & 0x7FFFu;
        const float ev = elds[s & (CH - 1)];
        const float c0 = __uint_as_float(cu << 16);
        const float c1 = __uint_as_float(cu & 0xFFFF0000u);
        const float Lc = dpp_shr1(ev, D1);
        const float n0 = fmaxf(c0, fminf(fminf(D0, Lp), Lc));
        const float n1 = fmaxf(c1, fminf(fminf(D1, D0), n0));
        const int ii = s - lane;
        const bool act = (u32)ii < (u32)N;
        Lp = (s0 && lane == 0) ? HUGEV : Lc;
        if (act) { D0 = n0; D1 = n1; }
        if (e63 && act) eout[s - s_lo] = n1;
      }
    }

    // (E) publish rows [s_lo-63, s_lo-32]: plain stores, data IS the flag
    if (do_edge) {
      asm volatile("s_waitcnt lgkmcnt(0)" ::: "memory");
      __builtin_amdgcn_sched_barrier(0);
      const int r = s_lo - 63 + lane;
      if (l32 && r >= 0 && r < N) {
        const float v = eout[lane];
        __hip_atomic_store(eB + r, v, __ATOMIC_RELAXED, __HIP_MEMORY_SCOPE_AGENT);
      }
    }
  }

  if (S == NSTRIP - 1 && lane == 63) out[0] = sqrtf(fmaxf(D1, 0.0f));
}

extern "C" void kernel_launch(void* const* d_in, const int* in_sizes, int n_in,
                              void* d_out, int out_size, void* d_ws, size_t ws_size,
                              hipStream_t stream) {
  const float* pred = (const float*)d_in[0];
  const float* tgt  = (const float*)d_in[1];
  char* ws = (char*)d_ws;
  u16* C2   = (u16*)ws;                                   // 32 MB row-major d2 (bf16)
  float* na = (float*)(ws + (size_t)N * N * 2);
  float* nb = na + N;
  float* edgeG = nb + N;                                  // 32*N floats, sentinel-init'd
  float* out = (float*)d_out;

  hipLaunchKernelGGL(norms_kernel, dim3(2048), dim3(256), 0, stream, pred, tgt, na, nb, edgeG);
  hipLaunchKernelGGL(gemm_kernel, dim3(32, 32), dim3(256), 0, stream, pred, tgt, na, nb, C2);
  hipLaunchKernelGGL(dp_kernel, dim3(NSTRIP), dim3(64), 0, stream, C2, edgeG, out);
}